// Round 1
// baseline (1205.289 us; speedup 1.0000x reference)
//
#include <hip/hip_runtime.h>
#include <hip/hip_bf16.h>

// Linear recurrence h_t = x_t@W + h_{t-1}@R via 3-level parallel scan (C=8).
// Precision: R split into 3 bf16 terms, h into 2; 4 MFMA products/step.
// h state lives in LDS fp32 [32][512] with XOR bank swizzle.

typedef float f32x4 __attribute__((ext_vector_type(4)));
typedef __bf16 bf16x8 __attribute__((ext_vector_type(8)));

#define TDIM 2048L
#define UDIM 512L

// XOR swizzle: kills the 16-way bank conflict of stride-512-dword rows.
__device__ __forceinline__ int hidx(int row, int col) {
  return row * 512 + (col ^ ((row & 7) << 3));
}

__device__ __forceinline__ f32x4 mfma16(bf16x8 a, bf16x8 b, f32x4 c) {
  return __builtin_amdgcn_mfma_f32_16x16x32_bf16(a, b, c, 0, 0, 0);
}

// One recurrence step for a [32,512] state block:
//   h_new = (HAS_ADD ? addend : 0) + (HAS_H ? h_old @ Bmat : 0)
// Bmat given as 3 bf16 split terms in MFMA-fragment order (each 512*512 elems).
// h_old is read from (and h_new written to) the swizzled LDS buffer; result
// optionally also written to global dst.
// 8 waves: wave w owns output columns [w*64, w*64+64).
template <bool HAS_H, bool HAS_ADD, bool WRITE_G>
__device__ __forceinline__ void rec_step(float* hbuf,
                                         const __bf16* __restrict__ bfrag,
                                         const float* add_base, long add_rs,
                                         float* dst_base, long dst_rs) {
  const int tid = threadIdx.x;
  const int l = tid & 63;
  const int w = tid >> 6;   // wave 0..7
  const int g = l >> 4;     // lane group 0..3
  const int li = l & 15;

  f32x4 acc[2][4] = {};

  if (HAS_H) {
    const long TS = 512 * 512;  // term stride (elements)
    bf16x8 bc[3][4], bn[3][4];
#pragma unroll
    for (int nt = 0; nt < 4; ++nt) {
      const long fo = (((long)(w * 4 + nt) * 16) * 64 + l) * 8;
#pragma unroll
      for (int t = 0; t < 3; ++t)
        bc[t][nt] = *(const bf16x8*)(bfrag + t * TS + fo);
    }
#pragma unroll 2
    for (int kk = 0; kk < 16; ++kk) {
      if (kk < 15) {  // prefetch next k-slice B fragments
#pragma unroll
        for (int nt = 0; nt < 4; ++nt) {
          const long fo = (((long)(w * 4 + nt) * 16 + kk + 1) * 64 + l) * 8;
#pragma unroll
          for (int t = 0; t < 3; ++t)
            bn[t][nt] = *(const bf16x8*)(bfrag + t * TS + fo);
        }
      }
      // A fragments: read 8 fp32 from LDS h, split into hi/lo bf16.
      bf16x8 a1[2], a2[2];
#pragma unroll
      for (int mt = 0; mt < 2; ++mt) {
        const float* p = &hbuf[hidx(mt * 16 + li, kk * 32 + g * 8)];
#pragma unroll
        for (int j = 0; j < 8; ++j) {
          const float v = p[j];
          const __bf16 hi = (__bf16)v;
          a1[mt][j] = hi;
          a2[mt][j] = (__bf16)(v - (float)hi);
        }
      }
      // 4 products: h1*r1, h1*r2, h2*r1, h1*r3 (each acc touched once per
      // round -> no back-to-back dependent MFMAs on the same register).
#pragma unroll
      for (int mt = 0; mt < 2; ++mt)
#pragma unroll
        for (int nt = 0; nt < 4; ++nt) acc[mt][nt] = mfma16(a1[mt], bc[0][nt], acc[mt][nt]);
#pragma unroll
      for (int mt = 0; mt < 2; ++mt)
#pragma unroll
        for (int nt = 0; nt < 4; ++nt) acc[mt][nt] = mfma16(a1[mt], bc[1][nt], acc[mt][nt]);
#pragma unroll
      for (int mt = 0; mt < 2; ++mt)
#pragma unroll
        for (int nt = 0; nt < 4; ++nt) acc[mt][nt] = mfma16(a2[mt], bc[0][nt], acc[mt][nt]);
#pragma unroll
      for (int mt = 0; mt < 2; ++mt)
#pragma unroll
        for (int nt = 0; nt < 4; ++nt) acc[mt][nt] = mfma16(a1[mt], bc[2][nt], acc[mt][nt]);
#pragma unroll
      for (int t = 0; t < 3; ++t)
#pragma unroll
        for (int nt = 0; nt < 4; ++nt) bc[t][nt] = bn[t][nt];
    }
  }

  f32x4 addv[2][4];
  if (HAS_ADD) {
#pragma unroll
    for (int mt = 0; mt < 2; ++mt)
#pragma unroll
      for (int nt = 0; nt < 4; ++nt) {
        const int col = w * 64 + nt * 16 + li;
        const float* ap = add_base + (long)(mt * 16 + g * 4) * add_rs + col;
#pragma unroll
        for (int r = 0; r < 4; ++r) addv[mt][nt][r] = ap[(long)r * add_rs];
      }
  }

  __syncthreads();  // all reads of hbuf done before overwrite
#pragma unroll
  for (int mt = 0; mt < 2; ++mt)
#pragma unroll
    for (int nt = 0; nt < 4; ++nt) {
      const int col = w * 64 + nt * 16 + li;
#pragma unroll
      for (int r = 0; r < 4; ++r) {
        float v = acc[mt][nt][r];
        if (HAS_ADD) v += addv[mt][nt][r];
        const int row = mt * 16 + g * 4 + r;
        hbuf[hidx(row, col)] = v;
        if (WRITE_G) dst_base[(long)row * dst_rs + col] = v;
      }
    }
  __syncthreads();
}

// ---- kernels -------------------------------------------------------------

// Split fp32 512x512 matrix into 3 bf16 terms, stored in MFMA B-fragment
// order: frag[(nt*16+kk)*64 + lane][8] with k = kk*32 + (lane>>4)*8 + j,
// n = nt*16 + (lane&15).
__global__ __launch_bounds__(512) void k_split(const float* __restrict__ m,
                                               __bf16* __restrict__ f) {
  const int idx = blockIdx.x * 512 + threadIdx.x;  // 0..262143
  const int j = idx & 7, l = (idx >> 3) & 63, kk = (idx >> 9) & 15, nt = idx >> 13;
  const int k = kk * 32 + (l >> 4) * 8 + j;
  const int n = nt * 16 + (l & 15);
  const float v = m[k * 512 + n];
  const __bf16 t1 = (__bf16)v;
  const float r1 = v - (float)t1;
  const __bf16 t2 = (__bf16)r1;
  const float r2 = r1 - (float)t2;
  const __bf16 t3 = (__bf16)r2;
  f[idx] = t1;
  f[262144 + idx] = t2;
  f[524288 + idx] = t3;
}

// C[blk rows 32] = A[blk rows 32] @ Bmat(frags). Used for xW and R-squarings.
__global__ __launch_bounds__(512) void k_gemm_rows(const float* __restrict__ a,
                                                   const __bf16* __restrict__ bf,
                                                   float* __restrict__ c) {
  __shared__ float hbuf[32 * 512];
  const long blk = blockIdx.x;
  const float* src = a + blk * (32 * 512);
  for (int i = threadIdx.x; i < 32 * 512; i += 512)
    hbuf[hidx(i >> 9, i & 511)] = src[i];
  __syncthreads();
  rec_step<true, false, true>(hbuf, bf, nullptr, 0, c + blk * (32 * 512), 512);
}

// Local (zero-init) chunk combine: S_out[c] = segment-combine of 8 entries.
__global__ __launch_bounds__(512) void k_local(const float* __restrict__ s_in,
                                               long in_es, long in_rs,
                                               const __bf16* __restrict__ bf,
                                               float* __restrict__ s_out) {
  __shared__ float hbuf[32 * 512];
  const long c = blockIdx.x;
  rec_step<false, true, false>(hbuf, bf, s_in + c * 8 * in_es, in_rs, nullptr, 0);
  for (int j = 1; j < 8; ++j)
    rec_step<true, true, false>(hbuf, bf, s_in + (c * 8 + j) * in_es, in_rs, nullptr, 0);
  float* dst = s_out + c * (32 * 512);
  for (int i = threadIdx.x; i < 32 * 512; i += 512)
    dst[i] = hbuf[hidx(i >> 9, i & 511)];
}

// Upper-level fix: expand entering states one level down.
__global__ __launch_bounds__(512) void k_fix_upper(const float* __restrict__ e_in,
                                                   const float* __restrict__ s_in,
                                                   const __bf16* __restrict__ bf,
                                                   float* __restrict__ e_out) {
  __shared__ float hbuf[32 * 512];
  const long m = blockIdx.x;
  const float* src = e_in + m * (32 * 512);
  for (int i = threadIdx.x; i < 32 * 512; i += 512)
    hbuf[hidx(i >> 9, i & 511)] = src[i];
  __syncthreads();
  for (int j = 0; j < 8; ++j) {
    float* dst = e_out + (m * 8 + j) * (32 * 512);
    for (int i = threadIdx.x; i < 32 * 512; i += 512)
      dst[i] = hbuf[hidx(i >> 9, i & 511)];
    if (j < 7)
      rec_step<true, true, false>(hbuf, bf, s_in + (m * 8 + j) * (32 * 512), 512, nullptr, 0);
  }
}

// Top serial level: 4 entries, seeds h0.
__global__ __launch_bounds__(512) void k_serial(const float* __restrict__ h0,
                                                const float* __restrict__ s3,
                                                const __bf16* __restrict__ a3f,
                                                float* __restrict__ e3) {
  __shared__ float hbuf[32 * 512];
  for (int i = threadIdx.x; i < 32 * 512; i += 512)
    hbuf[hidx(i >> 9, i & 511)] = h0[i];
  __syncthreads();
  for (int m = 0; m < 4; ++m) {
    float* dst = e3 + m * (32 * 512);
    for (int i = threadIdx.x; i < 32 * 512; i += 512)
      dst[i] = hbuf[hidx(i >> 9, i & 511)];
    __syncthreads();
    if (m < 3)
      rec_step<true, true, false>(hbuf, a3f, s3 + m * (32 * 512), 512, nullptr, 0);
  }
}

// Level-0 fix: re-run each chunk from its corrected entry state, write h_t.
// Reads xw from d_out and overwrites it in place with h.
__global__ __launch_bounds__(512) void k_fix0(const float* __restrict__ e1,
                                              float* out,
                                              const __bf16* __restrict__ rf) {
  __shared__ float hbuf[32 * 512];
  const long c = blockIdx.x;
  const float* src = e1 + c * (32 * 512);
  for (int i = threadIdx.x; i < 32 * 512; i += 512)
    hbuf[hidx(i >> 9, i & 511)] = src[i];
  __syncthreads();
  for (int j = 0; j < 8; ++j) {
    const long t = c * 8 + j;
    rec_step<true, true, true>(hbuf, rf, out + t * UDIM, TDIM * UDIM,
                               out + t * UDIM, TDIM * UDIM);
  }
}

extern "C" void kernel_launch(void* const* d_in, const int* in_sizes, int n_in,
                              void* d_out, int out_size, void* d_ws, size_t ws_size,
                              hipStream_t stream) {
  (void)in_sizes; (void)n_in; (void)out_size; (void)ws_size;
  const float* x  = (const float*)d_in[0];
  const float* W  = (const float*)d_in[1];
  const float* R  = (const float*)d_in[2];
  const float* h0 = (const float*)d_in[3];
  float* out = (float*)d_out;
  char* ws = (char*)d_ws;

  __bf16* Rf  = (__bf16*)(ws + 0x000000);   // 1.5 MB: frags of R
  __bf16* Wf  = (__bf16*)(ws + 0x180000);   // 1.5 MB: frags of W
  __bf16* A1f = (__bf16*)(ws + 0x300000);   // frags of R^8
  __bf16* A2f = (__bf16*)(ws + 0x480000);   // frags of R^64
  __bf16* A3f = (__bf16*)(ws + 0x600000);   // frags of R^512
  __bf16* Pf  = (__bf16*)(ws + 0x780000);   // scratch frags
  float* P    = (float*)(ws + 0x900000);    // 1 MB fp32 scratch
  float* Q    = (float*)(ws + 0xA00000);    // 1 MB fp32 scratch
  float* S1   = (float*)(ws + 0xB00000);    // 16 MB: 256 chunk sums
  float* E1   = (float*)(ws + 0x1B00000);   // 16 MB: 256 entering states
  float* S2   = (float*)(ws + 0x2B00000);   // 2 MB
  float* E2   = (float*)(ws + 0x2D00000);   // 2 MB
  float* S3   = (float*)(ws + 0x2F00000);   // 256 KB
  float* E3   = (float*)(ws + 0x2F40000);   // 256 KB

  // Splits of inputs.
  k_split<<<512, 512, 0, stream>>>(W, Wf);
  k_split<<<512, 512, 0, stream>>>(R, Rf);

  // xw = x @ W  (into d_out as scratch; fix0 overwrites with h later).
  k_gemm_rows<<<2048, 512, 0, stream>>>(x, Wf, out);

  // Level-0 local combine: S1[c] over t = 8c..8c+7.
  k_local<<<256, 512, 0, stream>>>(out, UDIM, TDIM * UDIM, Rf, S1);

  // Power chain: R^2..R^512 (fp32 via 4-product split GEMMs).
  k_gemm_rows<<<16, 512, 0, stream>>>(R, Rf, P);    // P = R^2
  k_split<<<512, 512, 0, stream>>>(P, Pf);
  k_gemm_rows<<<16, 512, 0, stream>>>(P, Pf, Q);    // Q = R^4
  k_split<<<512, 512, 0, stream>>>(Q, Pf);
  k_gemm_rows<<<16, 512, 0, stream>>>(Q, Pf, P);    // P = R^8
  k_split<<<512, 512, 0, stream>>>(P, A1f);
  k_gemm_rows<<<16, 512, 0, stream>>>(P, A1f, Q);   // Q = R^16
  k_split<<<512, 512, 0, stream>>>(Q, Pf);
  k_gemm_rows<<<16, 512, 0, stream>>>(Q, Pf, P);    // P = R^32
  k_split<<<512, 512, 0, stream>>>(P, Pf);
  k_gemm_rows<<<16, 512, 0, stream>>>(P, Pf, Q);    // Q = R^64
  k_split<<<512, 512, 0, stream>>>(Q, A2f);
  k_gemm_rows<<<16, 512, 0, stream>>>(Q, A2f, P);   // P = R^128
  k_split<<<512, 512, 0, stream>>>(P, Pf);
  k_gemm_rows<<<16, 512, 0, stream>>>(P, Pf, Q);    // Q = R^256
  k_split<<<512, 512, 0, stream>>>(Q, Pf);
  k_gemm_rows<<<16, 512, 0, stream>>>(Q, Pf, P);    // P = R^512
  k_split<<<512, 512, 0, stream>>>(P, A3f);

  // Upper-level combines.
  k_local<<<32, 512, 0, stream>>>(S1, 32 * UDIM, UDIM, A1f, S2);
  k_local<<<4, 512, 0, stream>>>(S2, 32 * UDIM, UDIM, A2f, S3);

  // Top serial + fixes back down.
  k_serial<<<1, 512, 0, stream>>>(h0, S3, A3f, E3);
  k_fix_upper<<<4, 512, 0, stream>>>(E3, S2, A2f, E2);
  k_fix_upper<<<32, 512, 0, stream>>>(E2, S1, A1f, E1);
  k_fix0<<<256, 512, 0, stream>>>(E1, out, Rf);
}

// Round 2
// 792.823 us; speedup vs baseline: 1.5202x; 1.5202x over previous
//
#include <hip/hip_runtime.h>
#include <hip/hip_bf16.h>

// Linear recurrence h_t = x_t@W + h_{t-1}@R, parallel scan.
// Level 0: chunks of 8 (serial in-block); above: binary tree (batched,
// col-split x8) over 256 chunk sums; transitions R^{8*2^k} from a fused
// squaring chain. Precision: R 3-term bf16 split / 4 products on the long
// E-chain; 2-term / 3 products for xW and the final fix pass.

typedef float f32x4 __attribute__((ext_vector_type(4)));
typedef __bf16 bf16x8 __attribute__((ext_vector_type(8)));

#define TDIM 2048L
#define UDIM 512L
#define ST 16384L       // elems per [32,512] state
#define TS 262144L      // elems per frag term
#define FE 786432L      // elems per 3-term frag matrix

// XOR swizzle for [32][512] fp32 LDS tiles (kills stride-2048B bank conflict)
__device__ __forceinline__ int hidx(int row, int col) {
  return row * 512 + (col ^ ((row & 7) << 3));
}

__device__ __forceinline__ f32x4 mfma16(bf16x8 a, bf16x8 b, f32x4 c) {
  return __builtin_amdgcn_mfma_f32_16x16x32_bf16(a, b, c, 0, 0, 0);
}

// ---- core step: h_new = (add?) + h_old @ Bfrag, h in swizzled LDS ---------
// Block = 64*? threads; NTW n-tiles per wave (16 waves*2 or 8 waves*4 = 32).
template <int NTERM, int NPROD, int NTW, bool HAS_H, bool HAS_ADD, bool WRITE_G>
__device__ __forceinline__ void rec_step(float* hbuf,
                                         const __bf16* __restrict__ bfrag,
                                         const float* add_base, long add_rs,
                                         float* dst_base, long dst_rs) {
  const int tid = threadIdx.x, l = tid & 63, w = tid >> 6, g = l >> 4, li = l & 15;
  f32x4 acc[2][NTW] = {};

  if (HAS_H) {
#pragma unroll 2
    for (int kk = 0; kk < 16; ++kk) {
      bf16x8 bc[NTERM][NTW];
#pragma unroll
      for (int q = 0; q < NTW; ++q) {
        const long fo = (((long)(w * NTW + q) * 16 + kk) * 64 + l) * 8;
#pragma unroll
        for (int t = 0; t < NTERM; ++t) bc[t][q] = *(const bf16x8*)(bfrag + (long)t * TS + fo);
      }
      bf16x8 a1[2], a2[2];
#pragma unroll
      for (int mt = 0; mt < 2; ++mt) {
        const float* p = &hbuf[hidx(mt * 16 + li, kk * 32 + g * 8)];
#pragma unroll
        for (int j = 0; j < 8; ++j) {
          const float v = p[j];
          const __bf16 hi = (__bf16)v;
          a1[mt][j] = hi;
          a2[mt][j] = (__bf16)(v - (float)hi);
        }
      }
#pragma unroll
      for (int mt = 0; mt < 2; ++mt)
#pragma unroll
        for (int q = 0; q < NTW; ++q) acc[mt][q] = mfma16(a1[mt], bc[0][q], acc[mt][q]);
#pragma unroll
      for (int mt = 0; mt < 2; ++mt)
#pragma unroll
        for (int q = 0; q < NTW; ++q) acc[mt][q] = mfma16(a1[mt], bc[1][q], acc[mt][q]);
      if (NPROD >= 3) {
#pragma unroll
        for (int mt = 0; mt < 2; ++mt)
#pragma unroll
          for (int q = 0; q < NTW; ++q) acc[mt][q] = mfma16(a2[mt], bc[0][q], acc[mt][q]);
      }
      if (NPROD >= 4) {
#pragma unroll
        for (int mt = 0; mt < 2; ++mt)
#pragma unroll
          for (int q = 0; q < NTW; ++q) acc[mt][q] = mfma16(a1[mt], bc[NTERM - 1][q], acc[mt][q]);
      }
    }
  }

  f32x4 addv[2][NTW];
  if (HAS_ADD) {
#pragma unroll
    for (int mt = 0; mt < 2; ++mt)
#pragma unroll
      for (int q = 0; q < NTW; ++q) {
        const int col = (w * NTW + q) * 16 + li;
        const float* ap = add_base + (long)(mt * 16 + g * 4) * add_rs + col;
#pragma unroll
        for (int r = 0; r < 4; ++r) addv[mt][q][r] = ap[(long)r * add_rs];
      }
  }

  __syncthreads();
#pragma unroll
  for (int mt = 0; mt < 2; ++mt)
#pragma unroll
    for (int q = 0; q < NTW; ++q) {
      const int col = (w * NTW + q) * 16 + li;
#pragma unroll
      for (int r = 0; r < 4; ++r) {
        float v = acc[mt][q][r];
        if (HAS_ADD) v += addv[mt][q][r];
        const int row = mt * 16 + g * 4 + r;
        hbuf[hidx(row, col)] = v;
        if (WRITE_G) dst_base[(long)row * dst_rs + col] = v;
      }
    }
  __syncthreads();
}

// ---- kernels --------------------------------------------------------------

// Split fp32 512x512 into 3 bf16 terms in MFMA B-fragment order.
__global__ __launch_bounds__(512) void k_split(const float* __restrict__ m,
                                               __bf16* __restrict__ f) {
  const int idx = blockIdx.x * 512 + threadIdx.x;
  const int j = idx & 7, l = (idx >> 3) & 63, kk = (idx >> 9) & 15, nt = idx >> 13;
  const int k = kk * 32 + (l >> 4) * 8 + j;
  const int n = nt * 16 + (l & 15);
  const float v = m[k * 512 + n];
  const __bf16 t1 = (__bf16)v;
  const float r1 = v - (float)t1;
  const __bf16 t2 = (__bf16)r1;
  f[idx] = t1;
  f[TS + idx] = t2;
  f[2 * TS + idx] = (__bf16)(r1 - (float)t2);
}

// xW: 32-row blocks, 2-term W, 3 products, 16 waves.
__global__ __launch_bounds__(1024) void k_xw(const float* __restrict__ x,
                                             const __bf16* __restrict__ wf,
                                             float* __restrict__ out) {
  __shared__ float hbuf[32 * 512];
  const long blk = blockIdx.x;
  const float* src = x + blk * ST;
  for (int i = threadIdx.x; i < 4096; i += 1024) {
    const int flat = i * 4, row = flat >> 9, col = flat & 511;
    *(f32x4*)&hbuf[hidx(row, col)] = *(const f32x4*)&src[flat];
  }
  __syncthreads();
  rec_step<2, 3, 2, true, false, true>(hbuf, wf, nullptr, 0, out + blk * ST, 512);
}

// Level-0 up-sweep: S1[c] = sum over 8 timesteps of chunk c.
__global__ __launch_bounds__(1024) void k_local(const float* __restrict__ xw,
                                                const __bf16* __restrict__ rf,
                                                float* __restrict__ sout) {
  __shared__ float hbuf[32 * 512];
  const long c = blockIdx.x;
  rec_step<3, 4, 2, false, true, false>(hbuf, rf, xw + c * 8 * UDIM, TDIM * UDIM, nullptr, 0);
  for (int j = 1; j < 8; ++j)
    rec_step<3, 4, 2, true, true, false>(hbuf, rf, xw + (c * 8 + j) * UDIM, TDIM * UDIM, nullptr, 0);
  float* dst = sout + c * ST;
  for (int i = threadIdx.x; i < 4096; i += 1024) {
    const int flat = i * 4, row = flat >> 9, col = flat & 511;
    *(f32x4*)&dst[flat] = *(const f32x4*)&hbuf[hidx(row, col)];
  }
}

// One-state x Bfrag product for tree/squaring blocks (wave owns 1 mt, 1 nt).
__device__ __forceinline__ f32x4 one_mm(const float* __restrict__ a,
                                        const __bf16* __restrict__ bf,
                                        int mt, int ntg) {
  const int tid = threadIdx.x, l = tid & 63, g = (l >> 4) & 3, li = l & 15;
  f32x4 acc = {};
#pragma unroll 2
  for (int kk = 0; kk < 16; ++kk) {
    const long fo = (((long)ntg * 16 + kk) * 64 + l) * 8;
    const bf16x8 b0 = *(const bf16x8*)(bf + fo);
    const bf16x8 b1 = *(const bf16x8*)(bf + TS + fo);
    const bf16x8 b2 = *(const bf16x8*)(bf + 2 * TS + fo);
    bf16x8 a1, a2;
    const float* p = a + (long)(mt * 16 + li) * 512 + kk * 32 + g * 8;
#pragma unroll
    for (int j = 0; j < 8; ++j) {
      const float v = p[j];
      const __bf16 hi = (__bf16)v;
      a1[j] = hi;
      a2[j] = (__bf16)(v - (float)hi);
    }
    acc = mfma16(a1, b0, acc);
    acc = mfma16(a1, b1, acc);
    acc = mfma16(a2, b0, acc);
    acc = mfma16(a1, b2, acc);
  }
  return acc;
}

// Squaring-chain: out = A @ Bfrag(A); writes fp32 + fused 3-term frag split.
// Grid 128: 16 row-groups x 8 col-groups. 8 waves: mt=w>>2, nt=cg*4+(w&3).
__global__ __launch_bounds__(512) void k_sq(const float* __restrict__ a,
                                            const __bf16* __restrict__ bf,
                                            float* __restrict__ of32,
                                            __bf16* __restrict__ ofr) {
  __shared__ float hbuf[32 * 512];
  const int b = blockIdx.x, rg = b >> 3, cg = b & 7;
  const int tid = threadIdx.x, l = tid & 63, w = tid >> 6, g = l >> 4, li = l & 15;
  const float* src = a + (long)rg * ST;
  for (int i = tid; i < 4096; i += 512) {
    const int flat = i * 4, row = flat >> 9, col = flat & 511;
    *(f32x4*)&hbuf[hidx(row, col)] = *(const f32x4*)&src[flat];
  }
  __syncthreads();
  const int mt = w >> 2, q = w & 3, ntg = cg * 4 + q;
  f32x4 acc = {};
#pragma unroll 2
  for (int kk = 0; kk < 16; ++kk) {
    const long fo = (((long)ntg * 16 + kk) * 64 + l) * 8;
    const bf16x8 b0 = *(const bf16x8*)(bf + fo);
    const bf16x8 b1 = *(const bf16x8*)(bf + TS + fo);
    const bf16x8 b2 = *(const bf16x8*)(bf + 2 * TS + fo);
    bf16x8 a1, a2;
    const float* pp = &hbuf[hidx(mt * 16 + li, kk * 32 + g * 8)];
#pragma unroll
    for (int j = 0; j < 8; ++j) {
      const float v = pp[j];
      const __bf16 hi = (__bf16)v;
      a1[j] = hi;
      a2[j] = (__bf16)(v - (float)hi);
    }
    acc = mfma16(a1, b0, acc);
    acc = mfma16(a1, b1, acc);
    acc = mfma16(a2, b0, acc);
    acc = mfma16(a1, b2, acc);
  }
  const int n = ntg * 16 + li;
#pragma unroll
  for (int r = 0; r < 4; ++r) {
    const int k = rg * 32 + mt * 16 + g * 4 + r;
    const float v = acc[r];
    of32[(long)k * 512 + n] = v;
    const __bf16 t1 = (__bf16)v;
    const float r1 = v - (float)t1;
    const __bf16 t2 = (__bf16)r1;
    const long fi = (((long)(n >> 4) * 16 + (k >> 5)) * 64 + ((k >> 3) & 3) * 16 + (n & 15)) * 8 + (k & 7);
    ofr[fi] = t1;
    ofr[TS + fi] = t2;
    ofr[2 * TS + fi] = (__bf16)(r1 - (float)t2);
  }
}

// Tree up-stage: out[p] = in[2p] @ M + in[2p+1]. Grid = pairs*8 (col-split).
__global__ __launch_bounds__(512) void k_pair(const float* __restrict__ in,
                                              const __bf16* __restrict__ bf,
                                              float* __restrict__ outb) {
  const int p = blockIdx.x >> 3, cs = blockIdx.x & 7;
  const int tid = threadIdx.x, l = tid & 63, w = tid >> 6, g = l >> 4, li = l & 15;
  const int mt = w >> 2, ntg = cs * 4 + (w & 3);
  const f32x4 acc = one_mm(in + (long)(2 * p) * ST, bf, mt, ntg);
  const float* addp = in + (long)(2 * p + 1) * ST;
  float* outp = outb + (long)p * ST;
  const int col = ntg * 16 + li;
#pragma unroll
  for (int r = 0; r < 4; ++r) {
    const int row = mt * 16 + g * 4 + r;
    outp[(long)row * 512 + col] = acc[r] + addp[(long)row * 512 + col];
  }
}

// Tree down-stage (in place into child-level buffer):
//   ulev[2p+1] = epar[p] @ M + ulev[2p]   (odd child entry)
//   ulev[2p]   = epar[p]                  (even child entry, after reads)
__global__ __launch_bounds__(512) void k_down(const float* __restrict__ epar,
                                              float* __restrict__ ulev,
                                              const __bf16* __restrict__ bf) {
  const int p = blockIdx.x >> 3, cs = blockIdx.x & 7;
  const int tid = threadIdx.x, l = tid & 63, w = tid >> 6, g = l >> 4, li = l & 15;
  const int mt = w >> 2, ntg = cs * 4 + (w & 3);
  const f32x4 acc = one_mm(epar + (long)p * ST, bf, mt, ntg);
  float* evp = ulev + (long)(2 * p) * ST;      // addend, then copy target
  float* outp = ulev + (long)(2 * p + 1) * ST;
  const int col = ntg * 16 + li;
  float cp[4];
#pragma unroll
  for (int r = 0; r < 4; ++r) {
    const int row = mt * 16 + g * 4 + r;
    const long off = (long)row * 512 + col;
    cp[r] = epar[(long)p * ST + off];
    outp[off] = acc[r] + evp[off];
  }
  __syncthreads();
#pragma unroll
  for (int r = 0; r < 4; ++r) {
    const int row = mt * 16 + g * 4 + r;
    evp[(long)row * 512 + col] = cp[r];
  }
}

// Final pass: re-run each chunk from corrected entry; xw -> h in place.
__global__ __launch_bounds__(1024) void k_fix0(const float* __restrict__ e0,
                                               float* out,
                                               const __bf16* __restrict__ rf) {
  __shared__ float hbuf[32 * 512];
  const long c = blockIdx.x;
  const float* src = e0 + c * ST;
  for (int i = threadIdx.x; i < 4096; i += 1024) {
    const int flat = i * 4, row = flat >> 9, col = flat & 511;
    *(f32x4*)&hbuf[hidx(row, col)] = *(const f32x4*)&src[flat];
  }
  __syncthreads();
  for (int j = 0; j < 8; ++j) {
    const long t = c * 8 + j;
    rec_step<2, 3, 2, true, true, true>(hbuf, rf, out + t * UDIM, TDIM * UDIM,
                                        out + t * UDIM, TDIM * UDIM);
  }
}

extern "C" void kernel_launch(void* const* d_in, const int* in_sizes, int n_in,
                              void* d_out, int out_size, void* d_ws, size_t ws_size,
                              hipStream_t stream) {
  (void)in_sizes; (void)n_in; (void)out_size; (void)ws_size;
  const float* x  = (const float*)d_in[0];
  const float* W  = (const float*)d_in[1];
  const float* R  = (const float*)d_in[2];
  const float* h0 = (const float*)d_in[3];
  float* out = (float*)d_out;

  // ws layout
  __bf16* F  = (__bf16*)d_ws;          // F[i] = frags of R^(2^i), i=0..10
  __bf16* Fw = F + 11 * FE;            // frags of W (2 terms used)
  float* P1 = (float*)(Fw + FE);
  float* P2 = P1 + TS;
  float* Sbuf = P2 + TS;               // 256 chunk sums -> entries E0
  float* Ub[8];
  {
    float* up = Sbuf + 256 * ST;
    for (int k = 1; k <= 7; ++k) { Ub[k] = up; up += (1L << (8 - k)) * ST; }
  }

  k_split<<<512, 512, 0, stream>>>(W, Fw);
  k_split<<<512, 512, 0, stream>>>(R, F);

  k_xw<<<2048, 1024, 0, stream>>>(x, Fw, out);
  k_local<<<256, 1024, 0, stream>>>(out, F, Sbuf);

  // squaring chain: R^2 .. R^1024, fused frag split
  {
    const float* pin = R;
    for (int i = 1; i <= 10; ++i) {
      float* po = (i & 1) ? P1 : P2;
      k_sq<<<128, 512, 0, stream>>>(pin, F + (long)(i - 1) * FE, po, F + (long)i * FE);
      pin = po;
    }
  }

  // tree up-sweep over 256 chunk sums (stage k uses M^(2^(k-1)) = F[k+2])
  for (int k = 1; k <= 7; ++k) {
    const float* inp = (k == 1) ? Sbuf : Ub[k - 1];
    k_pair<<<(1 << (8 - k)) * 8, 512, 0, stream>>>(inp, F + (long)(k + 2) * FE, Ub[k]);
  }

  // down-sweep: entries, in place into each child level (E0 lands in Sbuf)
  k_down<<<8, 512, 0, stream>>>(h0, Ub[7], F + 10L * FE);
  for (int k = 7; k >= 1; --k) {
    float* ul = (k == 1) ? Sbuf : Ub[k - 1];
    k_down<<<(1 << (8 - k)) * 8, 512, 0, stream>>>(Ub[k], ul, F + (long)(k + 2) * FE);
  }

  k_fix0<<<256, 1024, 0, stream>>>(Sbuf, out, F);
}